// Round 11
// baseline (465.076 us; speedup 1.0000x reference)
//
#include <hip/hip_runtime.h>
#include <hip/hip_bf16.h>

// VGAE forward, MI355X. Gather-based GCN; bf16 storage for all gathered operands
// (x, h, z, agg). CSR build via two-level binned counting sort (LDS atomics only,
// de-duplicated passes). Random-row kernels: full-row uint4 loads, deep MLP.
constexpr int N_ = 50000;
constexpr int E_ = 1600000;
constexpr int D_ = 128;   // embedding_dim == hidden_dim
constexpr int O_ = 64;    // out_embedding_dim
constexpr int NNZ_ = 16;
constexpr int V_ = 100000;
constexpr int NBIN_ = (N_ + 255) / 256;   // 196 coarse bins (dst>>8)

static __device__ __forceinline__ unsigned short f2bf(float f) {
    __hip_bfloat16 h = __float2bfloat16(f);
    return __builtin_bit_cast(unsigned short, h);
}
static __device__ __forceinline__ unsigned int pack2(float a, float b) {
    return (unsigned int)f2bf(a) | ((unsigned int)f2bf(b) << 16);
}
static __device__ __forceinline__ float blo(unsigned int u) { return __uint_as_float(u << 16); }
static __device__ __forceinline__ float bhi(unsigned int u) { return __uint_as_float(u & 0xffff0000u); }
static __device__ __forceinline__ float4 fma4(float s, float4 a, float4 b) {
    return make_float4(fmaf(s, a.x, b.x), fmaf(s, a.y, b.y),
                       fmaf(s, a.z, b.z), fmaf(s, a.w, b.w));
}

// ---------------------------------------------------------------------------
// 0. Convert fp32 emb table [V][128] -> bf16 (packed u32 pairs).
// ---------------------------------------------------------------------------
__global__ __launch_bounds__(256) void k_cvt(const float* __restrict__ emb,
                                             unsigned int* __restrict__ emb_bf) {
    int t = blockIdx.x * blockDim.x + threadIdx.x;
    if (t >= V_ * D_ / 8) return;
    float4 a = ((const float4*)emb)[t * 2];
    float4 b = ((const float4*)emb)[t * 2 + 1];
    uint4 o;
    o.x = pack2(a.x, a.y);
    o.y = pack2(a.z, a.w);
    o.z = pack2(b.x, b.y);
    o.w = pack2(b.z, b.w);
    ((uint4*)emb_bf)[t] = o;
}

// ---------------------------------------------------------------------------
// 1. EmbeddingBag(sum) + L2 normalize. Half-wave (32 lanes x uint2) per node,
//    2 nodes per wave.
// ---------------------------------------------------------------------------
__global__ __launch_bounds__(256) void k_embed(const int* __restrict__ fi,
                                               const float* __restrict__ fw,
                                               const unsigned int* __restrict__ emb_bf,
                                               unsigned int* __restrict__ x) {
    int lane = threadIdx.x & 63;
    int h = lane >> 5, c = lane & 31;
    int n = blockIdx.x * 8 + ((threadIdx.x >> 6) << 1) + h;
    if (n >= N_) return;
    float a0 = 0.f, a1 = 0.f, a2 = 0.f, a3 = 0.f;
    int base = n * NNZ_;
#pragma unroll
    for (int j = 0; j < NNZ_; ++j) {
        int idx  = fi[base + j];
        float w  = fw[base + j];
        uint2 r = ((const uint2*)emb_bf)[(size_t)idx * 32 + c];
        a0 = fmaf(w, blo(r.x), a0);
        a1 = fmaf(w, bhi(r.x), a1);
        a2 = fmaf(w, blo(r.y), a2);
        a3 = fmaf(w, bhi(r.y), a3);
    }
    float ss = a0 * a0 + a1 * a1 + a2 * a2 + a3 * a3;
#pragma unroll
    for (int o = 16; o; o >>= 1) ss += __shfl_xor(ss, o);
    float sc = 1.0f / fmaxf(sqrtf(ss), 1e-12f);
    ((uint2*)x)[(size_t)n * 32 + c] =
        make_uint2(pack2(a0 * sc, a1 * sc), pack2(a2 * sc, a3 * sc));
}

// ---------------------------------------------------------------------------
// 2a. Coarse-bin histogram of dst>>8: LDS hist per block; saves per-block hist
//     to global (reused by k_bin) + 196 global atomics for totals.
// ---------------------------------------------------------------------------
constexpr int EPB_ = 8192;   // edges per block
__global__ __launch_bounds__(256) void k_bhist(const int* __restrict__ dst,
                                               int* __restrict__ bin_total,
                                               int* __restrict__ blk_hist) {
    __shared__ int hist[256];
    int t = threadIdx.x;
    hist[t] = 0;
    __syncthreads();
    int e0 = blockIdx.x * EPB_;
#pragma unroll
    for (int i = 0; i < EPB_ / 256; ++i) {
        int e = e0 + i * 256 + t;
        if (e < E_) atomicAdd(&hist[dst[e] >> 8], 1);
    }
    __syncthreads();
    int v = hist[t];
    blk_hist[blockIdx.x * 256 + t] = v;
    if (t < NBIN_ && v) atomicAdd(&bin_total[t], v);
}

// ---------------------------------------------------------------------------
// 2b. Scan 196 bin counts -> coarse_start[197] (+ cursor copy); row_start[N]=E.
// ---------------------------------------------------------------------------
__global__ __launch_bounds__(256) void k_scan196(const int* __restrict__ bin_total,
                                                 int* __restrict__ coarse_start,
                                                 int* __restrict__ coarse_cursor,
                                                 int* __restrict__ row_start) {
    __shared__ int s[256];
    int t = threadIdx.x;
    int v = (t < NBIN_) ? bin_total[t] : 0;
    s[t] = v;
    __syncthreads();
    for (int o = 1; o < 256; o <<= 1) {
        int u = (t >= o) ? s[t - o] : 0;
        __syncthreads();
        s[t] += u;
        __syncthreads();
    }
    int excl = s[t] - v;
    if (t <= NBIN_) { coarse_start[t] = excl; coarse_cursor[t] = excl; }
    if (t == 0) row_start[N_] = E_;
}

// ---------------------------------------------------------------------------
// 2c. Coarse binning: reuse saved per-block histogram (no dst re-read for hist);
//     one global atomic per (block,bin) reserves space; edges written grouped
//     by bin, packed src|dlow<<16 (u32).
// ---------------------------------------------------------------------------
__global__ __launch_bounds__(256) void k_bin(const int* __restrict__ src,
                                             const int* __restrict__ dst,
                                             const int* __restrict__ blk_hist,
                                             int* __restrict__ coarse_cursor,
                                             unsigned int* __restrict__ binned) {
    __shared__ int base[256];
    int t = threadIdx.x;
    int hv = blk_hist[blockIdx.x * 256 + t];
    if (t < NBIN_ && hv) base[t] = atomicAdd(&coarse_cursor[t], hv);
    __syncthreads();
    int e0 = blockIdx.x * EPB_;
#pragma unroll
    for (int i = 0; i < EPB_ / 256; ++i) {
        int e = e0 + i * 256 + t;
        if (e < E_) {
            int d = dst[e];
            int pos = atomicAdd(&base[d >> 8], 1);
            binned[pos] = (unsigned int)src[e] | ((unsigned int)(d & 255) << 16);
        }
    }
}

// ---------------------------------------------------------------------------
// 2d. Merged node+fill: one block per coarse bin. Pass 1: LDS degree hist ->
//     disq/dinv/row_start (scan). Pass 2: re-sweep binned slice (L2-hot) and
//     scatter sorted_src via LDS cursors into a ~32KB window.
// ---------------------------------------------------------------------------
__global__ __launch_bounds__(256) void k_nodefill(const unsigned int* __restrict__ binned,
                                                  const int* __restrict__ coarse_start,
                                                  float* __restrict__ disq,
                                                  float* __restrict__ dinv,
                                                  int* __restrict__ row_start,
                                                  int* __restrict__ sorted_src) {
    __shared__ int hist[256], s[256], cur[256];
    int t = threadIdx.x;
    hist[t] = 0;
    __syncthreads();
    int beg = coarse_start[blockIdx.x], end = coarse_start[blockIdx.x + 1];
    for (int j = beg + t; j < end; j += 256)
        atomicAdd(&hist[(binned[j] >> 16) & 255], 1);
    __syncthreads();
    int v = hist[t];
    int n = (blockIdx.x << 8) + t;
    if (n < N_) {
        float deg = 1.0f + (float)v;
        disq[n] = rsqrtf(deg);
        dinv[n] = 1.0f / deg;
    }
    s[t] = v;
    __syncthreads();
    for (int o = 1; o < 256; o <<= 1) {
        int u = (t >= o) ? s[t - o] : 0;
        __syncthreads();
        s[t] += u;
        __syncthreads();
    }
    int rs = beg + (s[t] - v);
    if (n < N_) row_start[n] = rs;
    cur[t] = rs;
    __syncthreads();
    for (int j = beg + t; j < end; j += 256) {
        unsigned int b = binned[j];
        int pos = atomicAdd(&cur[(b >> 16) & 255], 1);
        sorted_src[pos] = (int)(b & 0xFFFFu);
    }
}

// ---------------------------------------------------------------------------
// 3. Gather aggregation from bf16 rows -> bf16 agg.
//    agg[n] = disq[n] * sum_j disq[s_j]*v[s_j]  +  dinv[n]*v[n]
//    Wave per node; quarter-wave (16 lanes x uint4) per edge. 32-edge unroll:
//    8 uint4 loads in flight per lane (~60 VGPR) to maximize MLP.
// ---------------------------------------------------------------------------
__global__ __launch_bounds__(256) void k_gather(const int* __restrict__ row_start,
                                                const int* __restrict__ sorted_src,
                                                const float* __restrict__ disq,
                                                const float* __restrict__ dinv,
                                                const unsigned int* __restrict__ v,
                                                unsigned int* __restrict__ agg) {
    int n = blockIdx.x * 4 + (threadIdx.x >> 6);
    if (n >= N_) return;
    int lane = threadIdx.x & 63;
    int g = lane >> 4, c = lane & 15;           // group 0..3, col 0..15
    const uint4* V = (const uint4*)v;           // row = 16 uint4 = 256B
    int beg = row_start[n], end = row_start[n + 1];
    float a0 = 0.f, a1 = 0.f, a2 = 0.f, a3 = 0.f;
    float a4 = 0.f, a5 = 0.f, a6 = 0.f, a7 = 0.f;
    int j = beg;
    // 32-edge unroll: 8 independent full-row loads in flight per lane
    for (; j + 31 < end; j += 32) {
        int ss[8]; float ww[8]; uint4 bb[8];
#pragma unroll
        for (int q = 0; q < 8; ++q) ss[q] = sorted_src[j + 4 * q + g];
#pragma unroll
        for (int q = 0; q < 8; ++q) ww[q] = disq[ss[q]];
#pragma unroll
        for (int q = 0; q < 8; ++q) bb[q] = V[(size_t)ss[q] * 16 + c];
#pragma unroll
        for (int q = 0; q < 8; ++q) {
            a0 = fmaf(ww[q], blo(bb[q].x), a0); a1 = fmaf(ww[q], bhi(bb[q].x), a1);
            a2 = fmaf(ww[q], blo(bb[q].y), a2); a3 = fmaf(ww[q], bhi(bb[q].y), a3);
            a4 = fmaf(ww[q], blo(bb[q].z), a4); a5 = fmaf(ww[q], bhi(bb[q].z), a5);
            a6 = fmaf(ww[q], blo(bb[q].w), a6); a7 = fmaf(ww[q], bhi(bb[q].w), a7);
        }
    }
    // 16-edge block
    for (; j + 15 < end; j += 16) {
        int ss[4]; float ww[4]; uint4 bb[4];
#pragma unroll
        for (int q = 0; q < 4; ++q) ss[q] = sorted_src[j + 4 * q + g];
#pragma unroll
        for (int q = 0; q < 4; ++q) ww[q] = disq[ss[q]];
#pragma unroll
        for (int q = 0; q < 4; ++q) bb[q] = V[(size_t)ss[q] * 16 + c];
#pragma unroll
        for (int q = 0; q < 4; ++q) {
            a0 = fmaf(ww[q], blo(bb[q].x), a0); a1 = fmaf(ww[q], bhi(bb[q].x), a1);
            a2 = fmaf(ww[q], blo(bb[q].y), a2); a3 = fmaf(ww[q], bhi(bb[q].y), a3);
            a4 = fmaf(ww[q], blo(bb[q].z), a4); a5 = fmaf(ww[q], bhi(bb[q].z), a5);
            a6 = fmaf(ww[q], blo(bb[q].w), a6); a7 = fmaf(ww[q], bhi(bb[q].w), a7);
        }
    }
    // tail: stride 4, group g takes edge j+g
    for (; j + g < end; j += 4) {
        int s0 = sorted_src[j + g];
        float w = disq[s0];
        uint4 b = V[(size_t)s0 * 16 + c];
        a0 = fmaf(w, blo(b.x), a0); a1 = fmaf(w, bhi(b.x), a1);
        a2 = fmaf(w, blo(b.y), a2); a3 = fmaf(w, bhi(b.y), a3);
        a4 = fmaf(w, blo(b.z), a4); a5 = fmaf(w, bhi(b.z), a5);
        a6 = fmaf(w, blo(b.w), a6); a7 = fmaf(w, bhi(b.w), a7);
    }
    a0 += __shfl_xor(a0, 16); a0 += __shfl_xor(a0, 32);
    a1 += __shfl_xor(a1, 16); a1 += __shfl_xor(a1, 32);
    a2 += __shfl_xor(a2, 16); a2 += __shfl_xor(a2, 32);
    a3 += __shfl_xor(a3, 16); a3 += __shfl_xor(a3, 32);
    a4 += __shfl_xor(a4, 16); a4 += __shfl_xor(a4, 32);
    a5 += __shfl_xor(a5, 16); a5 += __shfl_xor(a5, 32);
    a6 += __shfl_xor(a6, 16); a6 += __shfl_xor(a6, 32);
    a7 += __shfl_xor(a7, 16); a7 += __shfl_xor(a7, 32);
    if (g == 0) {
        float dq = disq[n], di = dinv[n];
        uint4 bs = V[(size_t)n * 16 + c];
        a0 = fmaf(di, blo(bs.x), a0 * dq); a1 = fmaf(di, bhi(bs.x), a1 * dq);
        a2 = fmaf(di, blo(bs.y), a2 * dq); a3 = fmaf(di, bhi(bs.y), a3 * dq);
        a4 = fmaf(di, blo(bs.z), a4 * dq); a5 = fmaf(di, bhi(bs.z), a5 * dq);
        a6 = fmaf(di, blo(bs.w), a6 * dq); a7 = fmaf(di, bhi(bs.w), a7 * dq);
        ((uint4*)agg)[(size_t)n * 16 + c] =
            make_uint4(pack2(a0, a1), pack2(a2, a3), pack2(a4, a5), pack2(a6, a7));
    }
}

// ---------------------------------------------------------------------------
// 4. Register-blocked GEMM: h = relu(agg @ W1 + b1), bf16 in (unpack to f32
//    LDS), bf16 out. f32 accumulate.
// ---------------------------------------------------------------------------
__global__ __launch_bounds__(256, 2) void k_gemm_relu(const unsigned int* __restrict__ ub,
                                                      const float* __restrict__ W,
                                                      const float* __restrict__ b,
                                                      unsigned short* __restrict__ hout) {
    __shared__ float lw[D_ * D_];     // 64 KiB
    __shared__ float lu[32 * D_];     // 16 KiB
    int tid = threadIdx.x;
    for (int t = tid; t < D_ * D_ / 4; t += 256)
        ((float4*)lw)[t] = ((const float4*)W)[t];

    int l  = tid & 31;
    int rl = ((tid >> 6) << 3) + (((tid >> 5) & 1) << 2);
    float4 bb = ((const float4*)b)[l];

    for (int tile = blockIdx.x; tile * 32 < N_; tile += gridDim.x) {
        int row0 = tile * 32;
        __syncthreads();
#pragma unroll
        for (int i = 0; i < 8; ++i) {
            int t = i * 256 + tid;              // 0..2047 u32 slots
            int r = t >> 6, slot = t & 63;
            int gr = row0 + r;
            unsigned int bv = (gr < N_) ? ub[(size_t)gr * 64 + slot] : 0u;
            lu[r * D_ + slot * 2]     = blo(bv);
            lu[r * D_ + slot * 2 + 1] = bhi(bv);
        }
        __syncthreads();
        float4 a0 = {0,0,0,0}, a1 = {0,0,0,0}, a2 = {0,0,0,0}, a3 = {0,0,0,0};
#pragma unroll 4
        for (int k4 = 0; k4 < 32; ++k4) {
            int k = k4 * 4;
            float4 w0 = ((const float4*)(lw + (k + 0) * D_))[l];
            float4 w1 = ((const float4*)(lw + (k + 1) * D_))[l];
            float4 w2 = ((const float4*)(lw + (k + 2) * D_))[l];
            float4 w3 = ((const float4*)(lw + (k + 3) * D_))[l];
            float4 u0 = ((const float4*)(lu + (rl + 0) * D_))[k4];
            float4 u1 = ((const float4*)(lu + (rl + 1) * D_))[k4];
            float4 u2 = ((const float4*)(lu + (rl + 2) * D_))[k4];
            float4 u3 = ((const float4*)(lu + (rl + 3) * D_))[k4];
            a0 = fma4(u0.x, w0, fma4(u0.y, w1, fma4(u0.z, w2, fma4(u0.w, w3, a0))));
            a1 = fma4(u1.x, w0, fma4(u1.y, w1, fma4(u1.z, w2, fma4(u1.w, w3, a1))));
            a2 = fma4(u2.x, w0, fma4(u2.y, w1, fma4(u2.z, w2, fma4(u2.w, w3, a2))));
            a3 = fma4(u3.x, w0, fma4(u3.y, w1, fma4(u3.z, w2, fma4(u3.w, w3, a3))));
        }
        float4 accs[4] = {a0, a1, a2, a3};
#pragma unroll
        for (int r = 0; r < 4; ++r) {
            int row = row0 + rl + r;
            if (row < N_) {
                float4 a = accs[r];
                ushort4 o;
                o.x = f2bf(fmaxf(a.x + bb.x, 0.f));
                o.y = f2bf(fmaxf(a.y + bb.y, 0.f));
                o.z = f2bf(fmaxf(a.z + bb.z, 0.f));
                o.w = f2bf(fmaxf(a.w + bb.w, 0.f));
                ((ushort4*)hout)[(size_t)row * 32 + l] = o;
            }
        }
    }
}

// ---------------------------------------------------------------------------
// 5. Fused mu/logstd GEMM (columns interleaved); z = mu + noise*exp(ls), bf16.
// ---------------------------------------------------------------------------
__global__ __launch_bounds__(256, 2) void k_gemm_z(const unsigned int* __restrict__ gb,
                                                   const float* __restrict__ Wmu,
                                                   const float* __restrict__ bmu,
                                                   const float* __restrict__ Wls,
                                                   const float* __restrict__ bls,
                                                   const float* __restrict__ noise,
                                                   unsigned int* __restrict__ z) {
    __shared__ float lw[D_ * D_];     // 64 KiB (interleaved Wmu|Wls)
    __shared__ float lu[32 * D_];     // 16 KiB
    int tid = threadIdx.x;
    for (int t = tid; t < D_ * 32; t += 256) {
        int k = t >> 5, j2 = t & 31;
        float2 m2 = ((const float2*)Wmu)[k * 32 + j2];
        float2 l2 = ((const float2*)Wls)[k * 32 + j2];
        ((float4*)lw)[t] = make_float4(m2.x, l2.x, m2.y, l2.y);
    }

    int l  = tid & 31;
    int rl = ((tid >> 6) << 3) + (((tid >> 5) & 1) << 2);
    float2 bm = ((const float2*)bmu)[l];
    float2 bl = ((const float2*)bls)[l];
    float4 bb = make_float4(bm.x, bl.x, bm.y, bl.y);

    for (int tile = blockIdx.x; tile * 32 < N_; tile += gridDim.x) {
        int row0 = tile * 32;
        __syncthreads();
#pragma unroll
        for (int i = 0; i < 8; ++i) {
            int t = i * 256 + tid;
            int r = t >> 6, slot = t & 63;
            int gr = row0 + r;
            unsigned int bv = (gr < N_) ? gb[(size_t)gr * 64 + slot] : 0u;
            lu[r * D_ + slot * 2]     = blo(bv);
            lu[r * D_ + slot * 2 + 1] = bhi(bv);
        }
        __syncthreads();
        float4 a0 = {0,0,0,0}, a1 = {0,0,0,0}, a2 = {0,0,0,0}, a3 = {0,0,0,0};
#pragma unroll 4
        for (int k4 = 0; k4 < 32; ++k4) {
            int k = k4 * 4;
            float4 w0 = ((const float4*)(lw + (k + 0) * D_))[l];
            float4 w1 = ((const float4*)(lw + (k + 1) * D_))[l];
            float4 w2 = ((const float4*)(lw + (k + 2) * D_))[l];
            float4 w3 = ((const float4*)(lw + (k + 3) * D_))[l];
            float4 u0 = ((const float4*)(lu + (rl + 0) * D_))[k4];
            float4 u1 = ((const float4*)(lu + (rl + 1) * D_))[k4];
            float4 u2 = ((const float4*)(lu + (rl + 2) * D_))[k4];
            float4 u3 = ((const float4*)(lu + (rl + 3) * D_))[k4];
            a0 = fma4(u0.x, w0, fma4(u0.y, w1, fma4(u0.z, w2, fma4(u0.w, w3, a0))));
            a1 = fma4(u1.x, w0, fma4(u1.y, w1, fma4(u1.z, w2, fma4(u1.w, w3, a1))));
            a2 = fma4(u2.x, w0, fma4(u2.y, w1, fma4(u2.z, w2, fma4(u2.w, w3, a2))));
            a3 = fma4(u3.x, w0, fma4(u3.y, w1, fma4(u3.z, w2, fma4(u3.w, w3, a3))));
        }
        float4 accs[4] = {a0, a1, a2, a3};
#pragma unroll
        for (int r = 0; r < 4; ++r) {
            int row = row0 + rl + r;
            if (row < N_) {
                float4 a = accs[r];
                float2 n2 = ((const float2*)noise)[(size_t)row * 32 + l];
                float z0 = (a.x + bb.x) + n2.x * expf(a.y + bb.y);
                float z1 = (a.z + bb.z) + n2.y * expf(a.w + bb.w);
                z[(size_t)row * 32 + l] = pack2(z0, z1);
            }
        }
    }
}

// ---------------------------------------------------------------------------
// 6. Decoder: logits[e] = dot(z[src], z[dst]) over 64 bf16.
//    8 lanes x uint4 per row; 4 edges batched per group -> 8 loads in flight;
//    lane 0 writes a coalesced float4 of 4 logits.
// ---------------------------------------------------------------------------
__global__ __launch_bounds__(256) void k_decode(const int* __restrict__ src,
                                                const int* __restrict__ dst,
                                                const unsigned int* __restrict__ z,
                                                float* __restrict__ out) {
    int l = threadIdx.x & 7;
    int e0 = blockIdx.x * 128 + ((threadIdx.x >> 3) << 2);   // E_ % 128 == 0
    int s0 = src[e0],     d0 = dst[e0];
    int s1 = src[e0 + 1], d1 = dst[e0 + 1];
    int s2 = src[e0 + 2], d2 = dst[e0 + 2];
    int s3 = src[e0 + 3], d3 = dst[e0 + 3];
    const uint4* Z = (const uint4*)z;
    uint4 za0 = Z[(size_t)s0 * 8 + l], zb0 = Z[(size_t)d0 * 8 + l];
    uint4 za1 = Z[(size_t)s1 * 8 + l], zb1 = Z[(size_t)d1 * 8 + l];
    uint4 za2 = Z[(size_t)s2 * 8 + l], zb2 = Z[(size_t)d2 * 8 + l];
    uint4 za3 = Z[(size_t)s3 * 8 + l], zb3 = Z[(size_t)d3 * 8 + l];
    float p0 = blo(za0.x) * blo(zb0.x) + bhi(za0.x) * bhi(zb0.x)
             + blo(za0.y) * blo(zb0.y) + bhi(za0.y) * bhi(zb0.y)
             + blo(za0.z) * blo(zb0.z) + bhi(za0.z) * bhi(zb0.z)
             + blo(za0.w) * blo(zb0.w) + bhi(za0.w) * bhi(zb0.w);
    float p1 = blo(za1.x) * blo(zb1.x) + bhi(za1.x) * bhi(zb1.x)
             + blo(za1.y) * blo(zb1.y) + bhi(za1.y) * bhi(zb1.y)
             + blo(za1.z) * blo(zb1.z) + bhi(za1.z) * bhi(zb1.z)
             + blo(za1.w) * blo(zb1.w) + bhi(za1.w) * bhi(zb1.w);
    float p2 = blo(za2.x) * blo(zb2.x) + bhi(za2.x) * bhi(zb2.x)
             + blo(za2.y) * blo(zb2.y) + bhi(za2.y) * bhi(zb2.y)
             + blo(za2.z) * blo(zb2.z) + bhi(za2.z) * bhi(zb2.z)
             + blo(za2.w) * blo(zb2.w) + bhi(za2.w) * bhi(zb2.w);
    float p3 = blo(za3.x) * blo(zb3.x) + bhi(za3.x) * bhi(zb3.x)
             + blo(za3.y) * blo(zb3.y) + bhi(za3.y) * bhi(zb3.y)
             + blo(za3.z) * blo(zb3.z) + bhi(za3.z) * bhi(zb3.z)
             + blo(za3.w) * blo(zb3.w) + bhi(za3.w) * bhi(zb3.w);
#pragma unroll
    for (int o = 4; o; o >>= 1) {
        p0 += __shfl_xor(p0, o);
        p1 += __shfl_xor(p1, o);
        p2 += __shfl_xor(p2, o);
        p3 += __shfl_xor(p3, o);
    }
    if (l == 0) ((float4*)out)[e0 >> 2] = make_float4(p0, p1, p2, p3);
}

// ---------------------------------------------------------------------------
extern "C" void kernel_launch(void* const* d_in, const int* in_sizes, int n_in,
                              void* d_out, int out_size, void* d_ws, size_t ws_size,
                              hipStream_t stream) {
    const int*   fi    = (const int*)d_in[0];
    const float* fw    = (const float*)d_in[2];
    const int*   ei    = (const int*)d_in[3];
    const float* noise = (const float*)d_in[4];
    const float* emb   = (const float*)d_in[5];
    const float* W1    = (const float*)d_in[6];
    const float* b1    = (const float*)d_in[7];
    const float* Wmu   = (const float*)d_in[8];
    const float* bmu   = (const float*)d_in[9];
    const float* Wls   = (const float*)d_in[10];
    const float* bls   = (const float*)d_in[11];
    float* out = (float*)d_out;

    const int* src = ei;
    const int* dst = ei + E_;

    // Workspace layout (4-byte units). The 25.6MB alias region serves, in
    // non-overlapping lifetime order: emb_bf (cvt->embed), binned (bin->nodefill),
    // agg bf16 (gather->gemm; first 12.8MB).
    float*        ws        = (float*)d_ws;
    unsigned int* aggb      = (unsigned int*)ws;                     // N*64 u32 = 12.8MB
    unsigned int* emb_bf    = (unsigned int*)ws;                     // V*64 u32 = 25.6MB
    unsigned int* binned    = (unsigned int*)ws;                     // E u32 = 6.4MB
    unsigned int* x         = (unsigned int*)ws + (size_t)V_ * 64;   // N*64 u32
    unsigned int* h         = x + (size_t)N_ * 64;                   // N*64 u32
    unsigned int* z         = h + (size_t)N_ * 64;                   // N*32 u32
    float*        disq      = (float*)(z + (size_t)N_ * 32);         // N
    float*        dinv      = disq + N_;                             // N
    int*          row_start = (int*)(dinv + N_);                     // N+1
    int*          sorted_src= row_start + (N_ + 1);                  // E
    int*          bin_total = sorted_src + E_;                       // 256
    int*          coarse_start  = bin_total + 256;                   // NBIN+1
    int*          coarse_cursor = coarse_start + 256;                // NBIN+1
    int*          blk_hist  = coarse_cursor + 256;                   // nblk*256

    const int nblk = (E_ + EPB_ - 1) / EPB_;   // 196

    hipMemsetAsync(bin_total, 0, 256 * sizeof(int), stream);

    k_cvt    <<<(V_ * D_ / 8 + 255) / 256, 256, 0, stream>>>(emb, emb_bf);
    k_embed  <<<(N_ + 7) / 8, 256, 0, stream>>>(fi, fw, emb_bf, x);
    k_bhist  <<<nblk,         256, 0, stream>>>(dst, bin_total, blk_hist);
    k_scan196<<<1,            256, 0, stream>>>(bin_total, coarse_start,
                                                coarse_cursor, row_start);
    k_bin    <<<nblk,         256, 0, stream>>>(src, dst, blk_hist,
                                                coarse_cursor, binned);
    k_nodefill<<<NBIN_,       256, 0, stream>>>(binned, coarse_start,
                                                disq, dinv, row_start, sorted_src);

    // GCN layer 1
    k_gather   <<<N_ / 4, 256, 0, stream>>>(row_start, sorted_src, disq, dinv, x, aggb);
    k_gemm_relu<<<512,    256, 0, stream>>>(aggb, W1, b1, (unsigned short*)h);

    // GCN layers 2+3 (one gather of h, fused mu/ls GEMM)
    k_gather <<<N_ / 4,   256, 0, stream>>>(row_start, sorted_src, disq, dinv, h, aggb);
    k_gemm_z <<<512,      256, 0, stream>>>(aggb, Wmu, bmu, Wls, bls, noise, z);

    // Decoder
    k_decode <<<E_ / 128, 256, 0, stream>>>(src, dst, z, out);
}